// Round 21
// baseline (91.730 us; speedup 1.0000x reference)
//
#include <hip/hip_runtime.h>
#include <hip/hip_bf16.h>

namespace {

constexpr int B_ = 8, S = 2048, D = 256, H = 4, HD = 64;
constexpr int M = B_ * S;  // 16384

typedef __attribute__((ext_vector_type(8))) short bf16x8;
typedef __attribute__((ext_vector_type(4))) short bf16x4;
typedef __attribute__((ext_vector_type(4))) float f32x4;
typedef __attribute__((ext_vector_type(16))) float f32x16;
typedef __attribute__((ext_vector_type(4))) unsigned uint4v;

__device__ inline short f2bf(float x) {
  __hip_bfloat16 h = __float2bfloat16(x);
  short s;
  __builtin_memcpy(&s, &h, 2);
  return s;
}

__device__ inline f32x4 mfma16(bf16x8 a, bf16x8 b, f32x4 c) {
  return __builtin_amdgcn_mfma_f32_16x16x32_bf16(a, b, c, 0, 0, 0);
}
__device__ inline f32x16 mfma32(bf16x8 a, bf16x8 b, f32x16 c) {
  return __builtin_amdgcn_mfma_f32_32x32x16_bf16(a, b, c, 0, 0, 0);
}

// raw 2^x
__device__ inline float exp2a(float x) {
  float r;
  asm("v_exp_f32 %0, %1" : "=v"(r) : "v"(x));
  return r;
}

// HW packed f32x2 -> bf16x2 (RNE)
__device__ inline unsigned cvtpk(float lo, float hi) {
  unsigned r;
  asm("v_cvt_pk_bf16_f32 %0, %1, %2" : "=v"(r) : "v"(lo), "v"(hi));
  return r;
}

__device__ inline bf16x4 pk4(float a, float b, float c, float d) {
  unsigned lo = cvtpk(a, b), hi = cvtpk(c, d);
  uint2 u{lo, hi};
  bf16x4 r;
  __builtin_memcpy(&r, &u, 8);
  return r;
}

// load 8 fp32, convert to bf16x8
__device__ inline bf16x8 ld_cvt8(const float* p) {
  float4 a = *(const float4*)p;
  float4 b = *(const float4*)(p + 4);
  uint4v u = {cvtpk(a.x, a.y), cvtpk(a.z, a.w), cvtpk(b.x, b.y), cvtpk(b.z, b.w)};
  bf16x8 r;
  __builtin_memcpy(&r, &u, 16);
  return r;
}

// ---------------------------------------------------------------------------
// Prep: 64 blocks transpose W{q,k,v,o} fp32[k][n] -> bf16 Wt[n][k].
// ---------------------------------------------------------------------------
__global__ __launch_bounds__(256) void prep_w_kernel(
    const float* __restrict__ Wq, const float* __restrict__ Wk,
    const float* __restrict__ Wv, const float* __restrict__ Wo,
    short* __restrict__ WqT, short* __restrict__ WkT,
    short* __restrict__ WvT, short* __restrict__ WoT) {
  const int blk = blockIdx.x, t = threadIdx.x;
  const int wq = blk >> 4, n0 = (blk & 15) * 16;
  const float* W = wq == 0 ? Wq : wq == 1 ? Wk : wq == 2 ? Wv : Wo;
  short* Wt = wq == 0 ? WqT : wq == 1 ? WkT : wq == 2 ? WvT : WoT;
#pragma unroll
  for (int j4 = 0; j4 < 4; ++j4) {
    float4 v = *(const float4*)(W + (size_t)t * 256 + n0 + j4 * 4);
    Wt[(n0 + j4 * 4 + 0) * 256 + t] = f2bf(v.x);
    Wt[(n0 + j4 * 4 + 1) * 256 + t] = f2bf(v.y);
    Wt[(n0 + j4 * 4 + 2) * 256 + t] = f2bf(v.z);
    Wt[(n0 + j4 * 4 + 3) * 256 + t] = f2bf(v.w);
  }
}

// ---------------------------------------------------------------------------
// QKV GEMM: x staged fp32 -> cvt_pk -> LDS. Q scale folds 1/8*log2e;
// V written [bh][d][s] via operand swap.
// ---------------------------------------------------------------------------
__global__ __launch_bounds__(256) void gemm_qkv_kernel(
    const float* __restrict__ x,
    const short* __restrict__ WqT, const short* __restrict__ WkT,
    const short* __restrict__ WvT,
    const float* __restrict__ bq, const float* __restrict__ bk,
    const float* __restrict__ bv,
    short* __restrict__ Qo, short* __restrict__ Ko, short* __restrict__ Vt) {
  const int bx = blockIdx.x;
  const int which = blockIdx.y;
  const short* Wt = which == 0 ? WqT : which == 1 ? WkT : WvT;
  const float* bias = which == 0 ? bq : which == 1 ? bk : bv;

  __shared__ short Xs[2][64 * 32];
  __shared__ short Ws[2][256 * 32];

  const int tid = threadIdx.x;
  const int wid = tid >> 6, lane = tid & 63;
  const int l15 = lane & 15, l4 = lane >> 4;
  const int nt0 = wid * 4;

  const float* xsrc = x + ((size_t)(bx * 64 + (tid >> 2))) * 256 + (tid & 3) * 8;
  const short* wsrc = Wt + ((size_t)(tid >> 2)) * 256 + (tid & 3) * 8;
  short* xdst0 = &Xs[0][tid * 8];
  short* xdst1 = &Xs[1][tid * 8];
  short* wdst0 = &Ws[0][tid * 8];
  short* wdst1 = &Ws[1][tid * 8];

  bf16x8 xr, wr[4];
  xr = ld_cvt8(xsrc);
#pragma unroll
  for (int p = 0; p < 4; ++p) wr[p] = *(const bf16x8*)(wsrc + (size_t)p * 64 * 256);
  *(bf16x8*)xdst0 = xr;
#pragma unroll
  for (int p = 0; p < 4; ++p) *(bf16x8*)(wdst0 + p * 2048) = wr[p];
  __syncthreads();

  f32x4 acc[4][4];
#pragma unroll
  for (int i = 0; i < 4; ++i)
#pragma unroll
    for (int mh = 0; mh < 4; ++mh) acc[i][mh] = f32x4{0.f, 0.f, 0.f, 0.f};

  for (int ks = 0; ks < 8; ++ks) {
    const int cur = ks & 1;
    if (ks < 7) {
      xr = ld_cvt8(xsrc + (ks + 1) * 32);
#pragma unroll
      for (int p = 0; p < 4; ++p)
        wr[p] = *(const bf16x8*)(wsrc + (size_t)p * 64 * 256 + (ks + 1) * 32);
    }
    bf16x8 wf[4], xf[4];
#pragma unroll
    for (int i = 0; i < 4; ++i)
      wf[i] = *(const bf16x8*)&Ws[cur][((nt0 + i) * 16 + l15) * 32 + l4 * 8];
#pragma unroll
    for (int mh = 0; mh < 4; ++mh)
      xf[mh] = *(const bf16x8*)&Xs[cur][(mh * 16 + l15) * 32 + l4 * 8];
    if (which == 2) {
#pragma unroll
      for (int i = 0; i < 4; ++i)
#pragma unroll
        for (int mh = 0; mh < 4; ++mh)
          acc[i][mh] = mfma16(xf[mh], wf[i], acc[i][mh]);  // D[m][n]
    } else {
#pragma unroll
      for (int i = 0; i < 4; ++i)
#pragma unroll
        for (int mh = 0; mh < 4; ++mh)
          acc[i][mh] = mfma16(wf[i], xf[mh], acc[i][mh]);  // D[n][m]
    }
    if (ks < 7) {
      short* xd = (cur ? xdst0 : xdst1);
      short* wd = (cur ? wdst0 : wdst1);
      *(bf16x8*)xd = xr;
#pragma unroll
      for (int p = 0; p < 4; ++p) *(bf16x8*)(wd + p * 2048) = wr[p];
    }
    __syncthreads();
  }

  if (which == 2) {
    const int m0 = bx * 64 + l4 * 4;
#pragma unroll
    for (int i = 0; i < 4; ++i) {
      const int n = (nt0 + i) * 16 + l15;
      const float bi = bias[n];
      const int h = n >> 6, d = n & 63;
#pragma unroll
      for (int mh = 0; mh < 4; ++mh) {
        const int m = m0 + mh * 16;
        const int bb = m >> 11, s0 = m & 2047;
        bf16x4 r = pk4(acc[i][mh][0] + bi, acc[i][mh][1] + bi,
                       acc[i][mh][2] + bi, acc[i][mh][3] + bi);
        *(bf16x4*)(Vt + (((size_t)bb * H + h) * HD + d) * S + s0) = r;
      }
    }
  } else {
    const float scale = which == 0 ? 0.18033688011112042f : 1.0f;  // 1/8*log2e
    short* outp = which == 0 ? Qo : Ko;
#pragma unroll
    for (int i = 0; i < 4; ++i) {
      const int n0 = (nt0 + i) * 16 + l4 * 4;
      float4 bi = *(const float4*)(bias + n0);
      const int h = n0 >> 6, d0 = n0 & 63;
#pragma unroll
      for (int mh = 0; mh < 4; ++mh) {
        const int m = bx * 64 + mh * 16 + l15;
        const int bb = m >> 11, s = m & 2047;
        bf16x4 r = pk4((acc[i][mh][0] + bi.x) * scale, (acc[i][mh][1] + bi.y) * scale,
                       (acc[i][mh][2] + bi.z) * scale, (acc[i][mh][3] + bi.w) * scale);
        *(bf16x4*)(outp + (((size_t)bb * H + h) * S + s) * HD + d0) = r;
      }
    }
  }
}

// ---------------------------------------------------------------------------
// Split-KV merge: Abf[m][256] = round_bf16((O0+O1) / (l0+l1)).
// Opart layout [sp][bh][q][64] fp32; lpart [sp][bh][2048] fp32.
// (Proven in R11/R13: passed at absmax 6.1e-5.)
// ---------------------------------------------------------------------------
__global__ __launch_bounds__(256) void merge_kernel(
    const float* __restrict__ O0, const float* __restrict__ O1,
    const float* __restrict__ l0, const float* __restrict__ l1,
    short* __restrict__ Abf) {
  const size_t g = ((size_t)blockIdx.x * 256 + threadIdx.x) * 8;  // over 32*2048*64
  const int bh = (int)(g >> 17);
  const int rem = (int)(g & 131071);
  const int q = rem >> 6, d = rem & 63;
  const float iv = 1.0f / (l0[(size_t)bh * 2048 + q] + l1[(size_t)bh * 2048 + q]);
  float4 a0 = *(const float4*)(O0 + g);
  float4 a1 = *(const float4*)(O0 + g + 4);
  float4 b0 = *(const float4*)(O1 + g);
  float4 b1 = *(const float4*)(O1 + g + 4);
  uint4v u = {cvtpk((a0.x + b0.x) * iv, (a0.y + b0.y) * iv),
              cvtpk((a0.z + b0.z) * iv, (a0.w + b0.w) * iv),
              cvtpk((a1.x + b1.x) * iv, (a1.y + b1.y) * iv),
              cvtpk((a1.z + b1.z) * iv, (a1.w + b1.w) * iv)};
  bf16x8 r;
  __builtin_memcpy(&r, &u, 16);
  const int b = bh >> 2, h = bh & 3;
  *(bf16x8*)(Abf + ((size_t)b * 2048 + q) * 256 + h * 64 + d) = r;
}

// ---------------------------------------------------------------------------
// Out projection GEMM (bf16 A in, fp32 out)
// ---------------------------------------------------------------------------
__global__ __launch_bounds__(256) void gemm_out_kernel(
    const short* __restrict__ Abf, const short* __restrict__ WoT,
    const float* __restrict__ bo, float* __restrict__ out) {
  const int bx = blockIdx.x;
  __shared__ short Xs[2][64 * 32];
  __shared__ short Ws[2][256 * 32];

  const int tid = threadIdx.x;
  const int wid = tid >> 6, lane = tid & 63;
  const int l15 = lane & 15, l4 = lane >> 4;
  const int nt0 = wid * 4;

  const short* xsrc = Abf + ((size_t)(bx * 64 + (tid >> 2))) * 256 + (tid & 3) * 8;
  const short* wsrc = WoT + ((size_t)(tid >> 2)) * 256 + (tid & 3) * 8;
  short* xdst0 = &Xs[0][tid * 8];
  short* xdst1 = &Xs[1][tid * 8];
  short* wdst0 = &Ws[0][tid * 8];
  short* wdst1 = &Ws[1][tid * 8];

  bf16x8 xr, wr[4];
  xr = *(const bf16x8*)xsrc;
#pragma unroll
  for (int p = 0; p < 4; ++p) wr[p] = *(const bf16x8*)(wsrc + (size_t)p * 64 * 256);
  *(bf16x8*)xdst0 = xr;
#pragma unroll
  for (int p = 0; p < 4; ++p) *(bf16x8*)(wdst0 + p * 2048) = wr[p];
  __syncthreads();

  f32x4 acc[4][4];
#pragma unroll
  for (int i = 0; i < 4; ++i)
#pragma unroll
    for (int mh = 0; mh < 4; ++mh) acc[i][mh] = f32x4{0.f, 0.f, 0.f, 0.f};

  for (int ks = 0; ks < 8; ++ks) {
    const int cur = ks & 1;
    if (ks < 7) {
      xr = *(const bf16x8*)(xsrc + (ks + 1) * 32);
#pragma unroll
      for (int p = 0; p < 4; ++p)
        wr[p] = *(const bf16x8*)(wsrc + (size_t)p * 64 * 256 + (ks + 1) * 32);
    }
    bf16x8 wf[4], xf[4];
#pragma unroll
    for (int i = 0; i < 4; ++i)
      wf[i] = *(const bf16x8*)&Ws[cur][((nt0 + i) * 16 + l15) * 32 + l4 * 8];
#pragma unroll
    for (int mh = 0; mh < 4; ++mh)
      xf[mh] = *(const bf16x8*)&Xs[cur][(mh * 16 + l15) * 32 + l4 * 8];
#pragma unroll
    for (int i = 0; i < 4; ++i)
#pragma unroll
      for (int mh = 0; mh < 4; ++mh)
        acc[i][mh] = mfma16(wf[i], xf[mh], acc[i][mh]);
    if (ks < 7) {
      short* xd = (cur ? xdst0 : xdst1);
      short* wd = (cur ? wdst0 : wdst1);
      *(bf16x8*)xd = xr;
#pragma unroll
      for (int p = 0; p < 4; ++p) *(bf16x8*)(wd + p * 2048) = wr[p];
    }
    __syncthreads();
  }

#pragma unroll
  for (int i = 0; i < 4; ++i) {
    const int n0 = (nt0 + i) * 16 + l4 * 4;
    float4 bi = *(const float4*)(bo + n0);
#pragma unroll
    for (int mh = 0; mh < 4; ++mh) {
      const int m = bx * 64 + mh * 16 + l15;
      float4 r;
      r.x = acc[i][mh][0] + bi.x;
      r.y = acc[i][mh][1] + bi.y;
      r.z = acc[i][mh][2] + bi.z;
      r.w = acc[i][mh][3] + bi.w;
      *(float4*)(out + (size_t)m * 256 + n0) = r;
    }
  }
}

// ---------------------------------------------------------------------------
// Flash attention v17: EXACT R17/R20 schedule (112 VGPR natural, PV deferred
// by 2, exp deferred by 1, packed 8KB tiles, K dbuf + V tri-buf, single
// barrier) + split-KV x2 via blockIdx.y. NO launch-bounds cap: the proven
// 112-reg body allows 4 waves/SIMD; LDS 40960 x 4 = exactly 160KB -> grid
// 1024 gives 4 blocks/CU (R11/R13 failures were cap-induced spill/squeeze,
// not split-induced). fp32 partial O + l (R13-proven numerics); merge in a
// standalone kernel.
// ---------------------------------------------------------------------------
__global__ __launch_bounds__(256) void attn_kernel17(
    const short* __restrict__ Q, const short* __restrict__ K,
    const short* __restrict__ VT, float* __restrict__ Opart,
    float* __restrict__ lpart) {
  const int lin = blockIdx.x;   // 512
  const int bh = lin & 31;      // same-bh blocks land on same XCD
  const int qt = lin >> 5;      // 0..15
  const int sp = blockIdx.y;    // split 0/1
  const int tid = threadIdx.x, wid = tid >> 6, lane = tid & 63;
  const int q31 = lane & 31, h = lane >> 5;
  constexpr int NT = 16;  // KV tiles per split

  __shared__ short Ks[2][32 * 128];  // packed [64][64] tiles, 8KB each
  __shared__ short Vs[3][32 * 128];

  const short* Kgs = K + (size_t)bh * S * HD + (size_t)sp * 1024 * HD;
  const short* Vg = VT + (size_t)bh * HD * S;
  const int vcol0 = sp * 1024;
  const int qrow = qt * 128 + wid * 32;

  const short* Qg = Q + ((size_t)bh * S + qrow + q31) * HD + h * 8;
  bf16x8 qf[4];
#pragma unroll
  for (int ds = 0; ds < 4; ++ds) qf[ds] = *(const bf16x8*)(Qg + ds * 16);

  bf16x8 ones;
#pragma unroll
  for (int i = 0; i < 8; ++i) ones[i] = (short)0x3F80;

  const int srow = tid >> 2;
  const int pr = srow & 31;
  const int scol = (tid & 3) * 16;
  const int cb0 = ((srow >> 5) << 6) + scol;
  const int swz = (pr & 15) * 8;
  const int c0 = cb0 ^ swz;
  const int c1 = (cb0 + 8) ^ swz;
  const int sbase = pr * 128;

  const int fs = (q31 & 15) * 8;
  int colA[4], colB[4];
#pragma unroll
  for (int ds = 0; ds < 4; ++ds) {
    colA[ds] = (ds * 16 + h * 8) ^ fs;
    colB[ds] = (64 + ds * 16 + h * 8) ^ fs;
  }
  const int rbase = q31 * 128;

  bf16x8 kr0, kr1, vr0, vr1;
  kr0 = *(const bf16x8*)(Kgs + (size_t)srow * HD + scol);
  kr1 = *(const bf16x8*)(Kgs + (size_t)srow * HD + scol + 8);
  *(bf16x8*)&Ks[0][sbase + c0] = kr0;
  *(bf16x8*)&Ks[0][sbase + c1] = kr1;
  {
    const short* Kn = Kgs + (size_t)64 * HD;
    kr0 = *(const bf16x8*)(Kn + (size_t)srow * HD + scol);
    kr1 = *(const bf16x8*)(Kn + (size_t)srow * HD + scol + 8);
    vr0 = *(const bf16x8*)(Vg + (size_t)srow * S + vcol0 + scol);
    vr1 = *(const bf16x8*)(Vg + (size_t)srow * S + vcol0 + scol + 8);
  }
  __syncthreads();

  f32x16 o0, o1, lsum, scA0, scA1, scB0, scB1;
#pragma unroll
  for (int i = 0; i < 16; ++i) { o0[i] = 0.f; o1[i] = 0.f; lsum[i] = 0.f; }
  bf16x8 pBA[4], pBB[4];

#define EXPPACK(S0, S1, PB)                                           \
  {                                                                   \
    _Pragma("unroll") for (int win = 0; win < 2; ++win) {             \
      const f32x16& sc = win ? (S1) : (S0);                           \
      float p[16];                                                    \
      _Pragma("unroll") for (int r = 0; r < 16; ++r)                  \
          p[r] = exp2a(sc[r]);                                        \
      unsigned w[8];                                                  \
      _Pragma("unroll") for (int i = 0; i < 8; ++i)                   \
          w[i] = cvtpk(p[2 * i], p[2 * i + 1]);                       \
      unsigned x0 = w[0], y0 = w[2], x1 = w[1], y1 = w[3];            \
      unsigned x2 = w[4], y2 = w[6], x3 = w[5], y3 = w[7];            \
      asm("v_permlane32_swap_b32 %0, %1" : "+v"(x0), "+v"(y0));       \
      asm("v_permlane32_swap_b32 %0, %1" : "+v"(x1), "+v"(y1));       \
      asm("v_permlane32_swap_b32 %0, %1" : "+v"(x2), "+v"(y2));       \
      asm("v_permlane32_swap_b32 %0, %1" : "+v"(x3), "+v"(y3));       \
      uint4v u0 = {x0, x1, y0, y1};                                   \
      uint4v u1 = {x2, x3, y2, y3};                                   \
      __builtin_memcpy(&PB[win * 2 + 0], &u0, 16);                    \
      __builtin_memcpy(&PB[win * 2 + 1], &u1, 16);                    \
    }                                                                 \
  }

#define QKBURST(KB, SCN0, SCN1)                                       \
  {                                                                   \
    _Pragma("unroll") for (int i = 0; i < 16; ++i) {                  \
      SCN0[i] = 0.f;                                                  \
      SCN1[i] = 0.f;                                                  \
    }                                                                 \
    const short* kb_ = (KB);                                          \
    _Pragma("unroll") for (int ds = 0; ds < 4; ++ds) {                \
      bf16x8 k0 = *(const bf16x8*)&kb_[rbase + colA[ds]];             \
      bf16x8 k1 = *(const bf16x8*)&kb_[rbase + colB[ds]];             \
      SCN0 = mfma32(k0, qf[ds], SCN0);                                \
      SCN1 = mfma32(k1, qf[ds], SCN1);                                \
    }                                                                 \
  }

#define PVBURST(VB, PB)                                               \
  {                                                                   \
    const short* vb_ = (VB);                                          \
    _Pragma("unroll") for (int ds = 0; ds < 4; ++ds) {                \
      bf16x8 v0 = *(const bf16x8*)&vb_[rbase + colA[ds]];             \
      bf16x8 v1 = *(const bf16x8*)&vb_[rbase + colB[ds]];             \
      o0 = mfma32(v0, PB[ds], o0);                                    \
      o1 = mfma32(v1, PB[ds], o1);                                    \
      lsum = mfma32(ones, PB[ds], lsum);                              \
    }                                                                 \
  }

#define STAGEWR(KT)                                                   \
  {                                                                   \
    if ((KT) + 1 < NT) {                                              \
      short* kw = &Ks[((KT) + 1) & 1][0];                             \
      *(bf16x8*)&kw[sbase + c0] = kr0;                                \
      *(bf16x8*)&kw[sbase + c1] = kr1;                                \
    }                                                                 \
    short* vw_ = &Vs[vw][0];                                          \
    *(bf16x8*)&vw_[sbase + c0] = vr0;                                 \
    *(bf16x8*)&vw_[sbase + c1] = vr1;                                 \
  }

#define LOADS(KT)                                                              \
  {                                                                            \
    if ((KT) + 1 < NT) {                                                       \
      const short* Kn = Kgs + (size_t)((KT) + 1) * 64 * HD;                    \
      kr0 = *(const bf16x8*)(Kn + (size_t)srow * HD + scol);                   \
      kr1 = *(const bf16x8*)(Kn + (size_t)srow * HD + scol + 8);               \
    }                                                                          \
    vr0 = *(const bf16x8*)(Vg + (size_t)srow * S + vcol0 + (KT) * 64 + scol);  \
    vr1 = *(const bf16x8*)(Vg + (size_t)srow * S + vcol0 + (KT) * 64 + scol + 8); \
  }

  int vw = 0;

  {
    __builtin_amdgcn_s_setprio(1);
    QKBURST(&Ks[0][0], scA0, scA1);
    __builtin_amdgcn_s_setprio(0);
    STAGEWR(0);
    __syncthreads();
    vw = 1;
  }

  {
    LOADS(1);
    __builtin_amdgcn_s_setprio(1);
    QKBURST(&Ks[1][0], scB0, scB1);
    __builtin_amdgcn_s_setprio(0);
    EXPPACK(scA0, scA1, pBA);
    STAGEWR(1);
    __syncthreads();
    vw = 2;
  }

#define STEP(KT, SCN0, SCN1, SCP0, SCP1, PBN, PBO)                    \
  {                                                                   \
    LOADS(KT);                                                        \
    const int vr2 = (vw + 1 == 3) ? 0 : vw + 1; /* (t-2)%3 */         \
    __builtin_amdgcn_s_setprio(1);                                    \
    QKBURST(&Ks[(KT)&1][0], SCN0, SCN1);                              \
    PVBURST(&Vs[vr2][0], PBO);                                        \
    __builtin_amdgcn_s_setprio(0);                                    \
    EXPPACK(SCP0, SCP1, PBN);                                         \
    STAGEWR(KT);                                                      \
    __syncthreads();                                                  \
    vw = (vw == 2) ? 0 : vw + 1;                                      \
  }

  // ---- main loop: t = 2..NT-1 (even/odd pairs; NT-2 = 14 even) ----
  for (int kt = 2; kt < NT; kt += 2) {
    STEP(kt, scA0, scA1, scB0, scB1, pBB, pBA);
    STEP(kt + 1, scB0, scB1, scA0, scA1, pBA, pBB);
  }

  // ---- epilogue ----
  // after loop: scB=sc(15), pBA=exp(sc(14)); PV done through t-2=13.
  // vw = 16%3 = 1. V(14) slot = (vw+1)%3 = 2; V(15) slot = (vw+2)%3 = 0.
  {
    __builtin_amdgcn_s_setprio(1);
    PVBURST(&Vs[2][0], pBA);  // PV(14)
    __builtin_amdgcn_s_setprio(0);
    EXPPACK(scB0, scB1, pBB);
    __builtin_amdgcn_s_setprio(1);
    PVBURST(&Vs[0][0], pBB);  // PV(15)
    __builtin_amdgcn_s_setprio(0);
  }
#undef STEP
#undef LOADS
#undef STAGEWR
#undef PVBURST
#undef QKBURST
#undef EXPPACK

  // ---- write fp32 partial O + l: layout [sp][bh][q][64] ----
  float* op = Opart + (((size_t)sp * 32 + bh) * 2048 + qrow + q31) * 64;
#pragma unroll
  for (int dt = 0; dt < 2; ++dt) {
    const f32x16& o = dt ? o1 : o0;
#pragma unroll
    for (int g = 0; g < 4; ++g) {
      const int d0 = dt * 32 + 8 * g + 4 * h;
      float4 r;
      r.x = o[4 * g + 0];
      r.y = o[4 * g + 1];
      r.z = o[4 * g + 2];
      r.w = o[4 * g + 3];
      *(float4*)(op + d0) = r;
    }
  }
  if (lane < 32) {
    lpart[((size_t)sp * 32 + bh) * 2048 + qrow + q31] = lsum[0];
  }
}

}  // namespace

extern "C" void kernel_launch(void* const* d_in, const int* in_sizes, int n_in,
                              void* d_out, int out_size, void* d_ws, size_t ws_size,
                              hipStream_t stream) {
  const float* x  = (const float*)d_in[0];
  const float* Wq = (const float*)d_in[1];
  const float* bq = (const float*)d_in[2];
  const float* Wk = (const float*)d_in[3];
  const float* bk = (const float*)d_in[4];
  const float* Wv = (const float*)d_in[5];
  const float* bv = (const float*)d_in[6];
  const float* Wo = (const float*)d_in[7];
  const float* bo = (const float*)d_in[8];
  float* out = (float*)d_out;

  const size_t per = (size_t)M * D;  // 4,194,304 elems
  short* WqT = (short*)d_ws;
  short* WkT = WqT + 256 * 256;
  short* WvT = WkT + 256 * 256;
  short* WoT = WvT + 256 * 256;
  short* Qbf = WoT + 256 * 256;
  short* Kbf = Qbf + per;
  short* Vt  = Kbf + per;            // [bh][d][s] bf16
  float* Op0 = (float*)(Vt + per);   // partial O split 0 (fp32)
  float* Op1 = Op0 + per;            // partial O split 1 (fp32)
  float* lp  = Op1 + per;            // l partials [2][32][2048] f32
  float* lp0 = lp;
  float* lp1 = lp + 32 * 2048;
  short* Abf = Qbf;                  // alias: Q dead after attn

  prep_w_kernel<<<64, 256, 0, stream>>>(Wq, Wk, Wv, Wo, WqT, WkT, WvT, WoT);
  gemm_qkv_kernel<<<dim3(256, 3), 256, 0, stream>>>(x, WqT, WkT, WvT, bq, bk, bv,
                                                    Qbf, Kbf, Vt);
  attn_kernel17<<<dim3(512, 2), 256, 0, stream>>>(Qbf, Kbf, Vt, Op0, lp);
  merge_kernel<<<2048, 256, 0, stream>>>(Op0, Op1, lp0, lp1, Abf);
  gemm_out_kernel<<<256, 256, 0, stream>>>(Abf, WoT, bo, out);
}

// Round 22
// 82.989 us; speedup vs baseline: 1.1053x; 1.1053x over previous
//
#include <hip/hip_runtime.h>
#include <hip/hip_bf16.h>

namespace {

constexpr int B_ = 8, S = 2048, D = 256, H = 4, HD = 64;
constexpr int M = B_ * S;  // 16384

typedef __attribute__((ext_vector_type(8))) short bf16x8;
typedef __attribute__((ext_vector_type(4))) short bf16x4;
typedef __attribute__((ext_vector_type(4))) float f32x4;
typedef __attribute__((ext_vector_type(16))) float f32x16;
typedef __attribute__((ext_vector_type(4))) unsigned uint4v;

__device__ inline short f2bf(float x) {
  __hip_bfloat16 h = __float2bfloat16(x);
  short s;
  __builtin_memcpy(&s, &h, 2);
  return s;
}

__device__ inline f32x4 mfma16(bf16x8 a, bf16x8 b, f32x4 c) {
  return __builtin_amdgcn_mfma_f32_16x16x32_bf16(a, b, c, 0, 0, 0);
}
__device__ inline f32x16 mfma32(bf16x8 a, bf16x8 b, f32x16 c) {
  return __builtin_amdgcn_mfma_f32_32x32x16_bf16(a, b, c, 0, 0, 0);
}

// raw 2^x
__device__ inline float exp2a(float x) {
  float r;
  asm("v_exp_f32 %0, %1" : "=v"(r) : "v"(x));
  return r;
}

// HW packed f32x2 -> bf16x2 (RNE)
__device__ inline unsigned cvtpk(float lo, float hi) {
  unsigned r;
  asm("v_cvt_pk_bf16_f32 %0, %1, %2" : "=v"(r) : "v"(lo), "v"(hi));
  return r;
}

__device__ inline bf16x4 pk4(float a, float b, float c, float d) {
  unsigned lo = cvtpk(a, b), hi = cvtpk(c, d);
  uint2 u{lo, hi};
  bf16x4 r;
  __builtin_memcpy(&r, &u, 8);
  return r;
}

// load 8 fp32, convert to bf16x8
__device__ inline bf16x8 ld_cvt8(const float* p) {
  float4 a = *(const float4*)p;
  float4 b = *(const float4*)(p + 4);
  uint4v u = {cvtpk(a.x, a.y), cvtpk(a.z, a.w), cvtpk(b.x, b.y), cvtpk(b.z, b.w)};
  bf16x8 r;
  __builtin_memcpy(&r, &u, 16);
  return r;
}

// ---------------------------------------------------------------------------
// Prep: 64 blocks transpose W{q,k,v,o} fp32[k][n] -> bf16 Wt[n][k].
// ---------------------------------------------------------------------------
__global__ __launch_bounds__(256) void prep_w_kernel(
    const float* __restrict__ Wq, const float* __restrict__ Wk,
    const float* __restrict__ Wv, const float* __restrict__ Wo,
    short* __restrict__ WqT, short* __restrict__ WkT,
    short* __restrict__ WvT, short* __restrict__ WoT) {
  const int blk = blockIdx.x, t = threadIdx.x;
  const int wq = blk >> 4, n0 = (blk & 15) * 16;
  const float* W = wq == 0 ? Wq : wq == 1 ? Wk : wq == 2 ? Wv : Wo;
  short* Wt = wq == 0 ? WqT : wq == 1 ? WkT : wq == 2 ? WvT : WoT;
#pragma unroll
  for (int j4 = 0; j4 < 4; ++j4) {
    float4 v = *(const float4*)(W + (size_t)t * 256 + n0 + j4 * 4);
    Wt[(n0 + j4 * 4 + 0) * 256 + t] = f2bf(v.x);
    Wt[(n0 + j4 * 4 + 1) * 256 + t] = f2bf(v.y);
    Wt[(n0 + j4 * 4 + 2) * 256 + t] = f2bf(v.z);
    Wt[(n0 + j4 * 4 + 3) * 256 + t] = f2bf(v.w);
  }
}

// ---------------------------------------------------------------------------
// QKV GEMM: x staged fp32 -> cvt_pk -> LDS. Q scale folds 1/8*log2e;
// V written [bh][d][s] via operand swap.
// ---------------------------------------------------------------------------
__global__ __launch_bounds__(256) void gemm_qkv_kernel(
    const float* __restrict__ x,
    const short* __restrict__ WqT, const short* __restrict__ WkT,
    const short* __restrict__ WvT,
    const float* __restrict__ bq, const float* __restrict__ bk,
    const float* __restrict__ bv,
    short* __restrict__ Qo, short* __restrict__ Ko, short* __restrict__ Vt) {
  const int bx = blockIdx.x;
  const int which = blockIdx.y;
  const short* Wt = which == 0 ? WqT : which == 1 ? WkT : WvT;
  const float* bias = which == 0 ? bq : which == 1 ? bk : bv;

  __shared__ short Xs[2][64 * 32];
  __shared__ short Ws[2][256 * 32];

  const int tid = threadIdx.x;
  const int wid = tid >> 6, lane = tid & 63;
  const int l15 = lane & 15, l4 = lane >> 4;
  const int nt0 = wid * 4;

  const float* xsrc = x + ((size_t)(bx * 64 + (tid >> 2))) * 256 + (tid & 3) * 8;
  const short* wsrc = Wt + ((size_t)(tid >> 2)) * 256 + (tid & 3) * 8;
  short* xdst0 = &Xs[0][tid * 8];
  short* xdst1 = &Xs[1][tid * 8];
  short* wdst0 = &Ws[0][tid * 8];
  short* wdst1 = &Ws[1][tid * 8];

  bf16x8 xr, wr[4];
  xr = ld_cvt8(xsrc);
#pragma unroll
  for (int p = 0; p < 4; ++p) wr[p] = *(const bf16x8*)(wsrc + (size_t)p * 64 * 256);
  *(bf16x8*)xdst0 = xr;
#pragma unroll
  for (int p = 0; p < 4; ++p) *(bf16x8*)(wdst0 + p * 2048) = wr[p];
  __syncthreads();

  f32x4 acc[4][4];
#pragma unroll
  for (int i = 0; i < 4; ++i)
#pragma unroll
    for (int mh = 0; mh < 4; ++mh) acc[i][mh] = f32x4{0.f, 0.f, 0.f, 0.f};

  for (int ks = 0; ks < 8; ++ks) {
    const int cur = ks & 1;
    if (ks < 7) {
      xr = ld_cvt8(xsrc + (ks + 1) * 32);
#pragma unroll
      for (int p = 0; p < 4; ++p)
        wr[p] = *(const bf16x8*)(wsrc + (size_t)p * 64 * 256 + (ks + 1) * 32);
    }
    bf16x8 wf[4], xf[4];
#pragma unroll
    for (int i = 0; i < 4; ++i)
      wf[i] = *(const bf16x8*)&Ws[cur][((nt0 + i) * 16 + l15) * 32 + l4 * 8];
#pragma unroll
    for (int mh = 0; mh < 4; ++mh)
      xf[mh] = *(const bf16x8*)&Xs[cur][(mh * 16 + l15) * 32 + l4 * 8];
    if (which == 2) {
#pragma unroll
      for (int i = 0; i < 4; ++i)
#pragma unroll
        for (int mh = 0; mh < 4; ++mh)
          acc[i][mh] = mfma16(xf[mh], wf[i], acc[i][mh]);  // D[m][n]
    } else {
#pragma unroll
      for (int i = 0; i < 4; ++i)
#pragma unroll
        for (int mh = 0; mh < 4; ++mh)
          acc[i][mh] = mfma16(wf[i], xf[mh], acc[i][mh]);  // D[n][m]
    }
    if (ks < 7) {
      short* xd = (cur ? xdst0 : xdst1);
      short* wd = (cur ? wdst0 : wdst1);
      *(bf16x8*)xd = xr;
#pragma unroll
      for (int p = 0; p < 4; ++p) *(bf16x8*)(wd + p * 2048) = wr[p];
    }
    __syncthreads();
  }

  if (which == 2) {
    const int m0 = bx * 64 + l4 * 4;
#pragma unroll
    for (int i = 0; i < 4; ++i) {
      const int n = (nt0 + i) * 16 + l15;
      const float bi = bias[n];
      const int h = n >> 6, d = n & 63;
#pragma unroll
      for (int mh = 0; mh < 4; ++mh) {
        const int m = m0 + mh * 16;
        const int bb = m >> 11, s0 = m & 2047;
        bf16x4 r = pk4(acc[i][mh][0] + bi, acc[i][mh][1] + bi,
                       acc[i][mh][2] + bi, acc[i][mh][3] + bi);
        *(bf16x4*)(Vt + (((size_t)bb * H + h) * HD + d) * S + s0) = r;
      }
    }
  } else {
    const float scale = which == 0 ? 0.18033688011112042f : 1.0f;  // 1/8*log2e
    short* outp = which == 0 ? Qo : Ko;
#pragma unroll
    for (int i = 0; i < 4; ++i) {
      const int n0 = (nt0 + i) * 16 + l4 * 4;
      float4 bi = *(const float4*)(bias + n0);
      const int h = n0 >> 6, d0 = n0 & 63;
#pragma unroll
      for (int mh = 0; mh < 4; ++mh) {
        const int m = bx * 64 + mh * 16 + l15;
        const int bb = m >> 11, s = m & 2047;
        bf16x4 r = pk4((acc[i][mh][0] + bi.x) * scale, (acc[i][mh][1] + bi.y) * scale,
                       (acc[i][mh][2] + bi.z) * scale, (acc[i][mh][3] + bi.w) * scale);
        *(bf16x4*)(outp + (((size_t)bb * H + h) * S + s) * HD + d0) = r;
      }
    }
  }
}

// ---------------------------------------------------------------------------
// Out projection GEMM (bf16 A in, fp32 out)
// ---------------------------------------------------------------------------
__global__ __launch_bounds__(256) void gemm_out_kernel(
    const short* __restrict__ Abf, const short* __restrict__ WoT,
    const float* __restrict__ bo, float* __restrict__ out) {
  const int bx = blockIdx.x;
  __shared__ short Xs[2][64 * 32];
  __shared__ short Ws[2][256 * 32];

  const int tid = threadIdx.x;
  const int wid = tid >> 6, lane = tid & 63;
  const int l15 = lane & 15, l4 = lane >> 4;
  const int nt0 = wid * 4;

  const short* xsrc = Abf + ((size_t)(bx * 64 + (tid >> 2))) * 256 + (tid & 3) * 8;
  const short* wsrc = WoT + ((size_t)(tid >> 2)) * 256 + (tid & 3) * 8;
  short* xdst0 = &Xs[0][tid * 8];
  short* xdst1 = &Xs[1][tid * 8];
  short* wdst0 = &Ws[0][tid * 8];
  short* wdst1 = &Ws[1][tid * 8];

  bf16x8 xr, wr[4];
  xr = *(const bf16x8*)xsrc;
#pragma unroll
  for (int p = 0; p < 4; ++p) wr[p] = *(const bf16x8*)(wsrc + (size_t)p * 64 * 256);
  *(bf16x8*)xdst0 = xr;
#pragma unroll
  for (int p = 0; p < 4; ++p) *(bf16x8*)(wdst0 + p * 2048) = wr[p];
  __syncthreads();

  f32x4 acc[4][4];
#pragma unroll
  for (int i = 0; i < 4; ++i)
#pragma unroll
    for (int mh = 0; mh < 4; ++mh) acc[i][mh] = f32x4{0.f, 0.f, 0.f, 0.f};

  for (int ks = 0; ks < 8; ++ks) {
    const int cur = ks & 1;
    if (ks < 7) {
      xr = *(const bf16x8*)(xsrc + (ks + 1) * 32);
#pragma unroll
      for (int p = 0; p < 4; ++p)
        wr[p] = *(const bf16x8*)(wsrc + (size_t)p * 64 * 256 + (ks + 1) * 32);
    }
    bf16x8 wf[4], xf[4];
#pragma unroll
    for (int i = 0; i < 4; ++i)
      wf[i] = *(const bf16x8*)&Ws[cur][((nt0 + i) * 16 + l15) * 32 + l4 * 8];
#pragma unroll
    for (int mh = 0; mh < 4; ++mh)
      xf[mh] = *(const bf16x8*)&Xs[cur][(mh * 16 + l15) * 32 + l4 * 8];
#pragma unroll
    for (int i = 0; i < 4; ++i)
#pragma unroll
      for (int mh = 0; mh < 4; ++mh)
        acc[i][mh] = mfma16(wf[i], xf[mh], acc[i][mh]);
    if (ks < 7) {
      short* xd = (cur ? xdst0 : xdst1);
      short* wd = (cur ? wdst0 : wdst1);
      *(bf16x8*)xd = xr;
#pragma unroll
      for (int p = 0; p < 4; ++p) *(bf16x8*)(wd + p * 2048) = wr[p];
    }
    __syncthreads();
  }

#pragma unroll
  for (int i = 0; i < 4; ++i) {
    const int n0 = (nt0 + i) * 16 + l4 * 4;
    float4 bi = *(const float4*)(bo + n0);
#pragma unroll
    for (int mh = 0; mh < 4; ++mh) {
      const int m = bx * 64 + mh * 16 + l15;
      float4 r;
      r.x = acc[i][mh][0] + bi.x;
      r.y = acc[i][mh][1] + bi.y;
      r.z = acc[i][mh][2] + bi.z;
      r.w = acc[i][mh][3] + bi.w;
      *(float4*)(out + (size_t)m * 256 + n0) = r;
    }
  }
}

// ---------------------------------------------------------------------------
// Flash attention v15 (R17/R20, proven 47.4us): PV deferred by 2, exp
// deferred by 1, packed 8KB tiles, K dbuf + V tri-buf, single barrier/tile.
// ---------------------------------------------------------------------------
__global__ __launch_bounds__(256) void attn_kernel15(
    const short* __restrict__ Q, const short* __restrict__ K,
    const short* __restrict__ VT, short* __restrict__ Abf) {
  const int lin = blockIdx.x;   // 512
  const int bh = lin & 31;      // same-bh blocks land on same XCD
  const int qt = lin >> 5;      // 0..15
  const int tid = threadIdx.x, wid = tid >> 6, lane = tid & 63;
  const int q31 = lane & 31, h = lane >> 5;
  constexpr int NT = S / 64;  // 32

  __shared__ short Ks[2][32 * 128];  // packed [64][64] tiles, 8KB each
  __shared__ short Vs[3][32 * 128];

  const short* Kg = K + (size_t)bh * S * HD;
  const short* Vg = VT + (size_t)bh * HD * S;
  const int qrow = qt * 128 + wid * 32;

  const short* Qg = Q + ((size_t)bh * S + qrow + q31) * HD + h * 8;
  bf16x8 qf[4];
#pragma unroll
  for (int ds = 0; ds < 4; ++ds) qf[ds] = *(const bf16x8*)(Qg + ds * 16);

  bf16x8 ones;
#pragma unroll
  for (int i = 0; i < 8; ++i) ones[i] = (short)0x3F80;

  const int srow = tid >> 2;
  const int pr = srow & 31;
  const int scol = (tid & 3) * 16;
  const int cb0 = ((srow >> 5) << 6) + scol;
  const int swz = (pr & 15) * 8;
  const int c0 = cb0 ^ swz;
  const int c1 = (cb0 + 8) ^ swz;
  const int sbase = pr * 128;

  const int fs = (q31 & 15) * 8;
  int colA[4], colB[4];
#pragma unroll
  for (int ds = 0; ds < 4; ++ds) {
    colA[ds] = (ds * 16 + h * 8) ^ fs;
    colB[ds] = (64 + ds * 16 + h * 8) ^ fs;
  }
  const int rbase = q31 * 128;

  bf16x8 kr0, kr1, vr0, vr1;
  kr0 = *(const bf16x8*)(Kg + (size_t)srow * HD + scol);
  kr1 = *(const bf16x8*)(Kg + (size_t)srow * HD + scol + 8);
  *(bf16x8*)&Ks[0][sbase + c0] = kr0;
  *(bf16x8*)&Ks[0][sbase + c1] = kr1;
  {
    const short* Kn = Kg + (size_t)64 * HD;
    kr0 = *(const bf16x8*)(Kn + (size_t)srow * HD + scol);
    kr1 = *(const bf16x8*)(Kn + (size_t)srow * HD + scol + 8);
    vr0 = *(const bf16x8*)(Vg + (size_t)srow * S + scol);
    vr1 = *(const bf16x8*)(Vg + (size_t)srow * S + scol + 8);
  }
  __syncthreads();

  f32x16 o0, o1, lsum, scA0, scA1, scB0, scB1;
#pragma unroll
  for (int i = 0; i < 16; ++i) { o0[i] = 0.f; o1[i] = 0.f; lsum[i] = 0.f; }
  bf16x8 pBA[4], pBB[4];

#define EXPPACK(S0, S1, PB)                                           \
  {                                                                   \
    _Pragma("unroll") for (int win = 0; win < 2; ++win) {             \
      const f32x16& sc = win ? (S1) : (S0);                           \
      float p[16];                                                    \
      _Pragma("unroll") for (int r = 0; r < 16; ++r)                  \
          p[r] = exp2a(sc[r]);                                        \
      unsigned w[8];                                                  \
      _Pragma("unroll") for (int i = 0; i < 8; ++i)                   \
          w[i] = cvtpk(p[2 * i], p[2 * i + 1]);                       \
      unsigned x0 = w[0], y0 = w[2], x1 = w[1], y1 = w[3];            \
      unsigned x2 = w[4], y2 = w[6], x3 = w[5], y3 = w[7];            \
      asm("v_permlane32_swap_b32 %0, %1" : "+v"(x0), "+v"(y0));       \
      asm("v_permlane32_swap_b32 %0, %1" : "+v"(x1), "+v"(y1));       \
      asm("v_permlane32_swap_b32 %0, %1" : "+v"(x2), "+v"(y2));       \
      asm("v_permlane32_swap_b32 %0, %1" : "+v"(x3), "+v"(y3));       \
      uint4v u0 = {x0, x1, y0, y1};                                   \
      uint4v u1 = {x2, x3, y2, y3};                                   \
      __builtin_memcpy(&PB[win * 2 + 0], &u0, 16);                    \
      __builtin_memcpy(&PB[win * 2 + 1], &u1, 16);                    \
    }                                                                 \
  }

#define QKBURST(KB, SCN0, SCN1)                                       \
  {                                                                   \
    _Pragma("unroll") for (int i = 0; i < 16; ++i) {                  \
      SCN0[i] = 0.f;                                                  \
      SCN1[i] = 0.f;                                                  \
    }                                                                 \
    const short* kb_ = (KB);                                          \
    _Pragma("unroll") for (int ds = 0; ds < 4; ++ds) {                \
      bf16x8 k0 = *(const bf16x8*)&kb_[rbase + colA[ds]];             \
      bf16x8 k1 = *(const bf16x8*)&kb_[rbase + colB[ds]];             \
      SCN0 = mfma32(k0, qf[ds], SCN0);                                \
      SCN1 = mfma32(k1, qf[ds], SCN1);                                \
    }                                                                 \
  }

#define PVBURST(VB, PB)                                               \
  {                                                                   \
    const short* vb_ = (VB);                                          \
    _Pragma("unroll") for (int ds = 0; ds < 4; ++ds) {                \
      bf16x8 v0 = *(const bf16x8*)&vb_[rbase + colA[ds]];             \
      bf16x8 v1 = *(const bf16x8*)&vb_[rbase + colB[ds]];             \
      o0 = mfma32(v0, PB[ds], o0);                                    \
      o1 = mfma32(v1, PB[ds], o1);                                    \
      lsum = mfma32(ones, PB[ds], lsum);                              \
    }                                                                 \
  }

#define STAGEWR(KT)                                                   \
  {                                                                   \
    if ((KT) + 1 < NT) {                                              \
      short* kw = &Ks[((KT) + 1) & 1][0];                             \
      *(bf16x8*)&kw[sbase + c0] = kr0;                                \
      *(bf16x8*)&kw[sbase + c1] = kr1;                                \
    }                                                                 \
    short* vw_ = &Vs[vw][0];                                          \
    *(bf16x8*)&vw_[sbase + c0] = vr0;                                 \
    *(bf16x8*)&vw_[sbase + c1] = vr1;                                 \
  }

#define LOADS(KT)                                                          \
  {                                                                        \
    if ((KT) + 1 < NT) {                                                   \
      const short* Kn = Kg + (size_t)((KT) + 1) * 64 * HD;                 \
      kr0 = *(const bf16x8*)(Kn + (size_t)srow * HD + scol);               \
      kr1 = *(const bf16x8*)(Kn + (size_t)srow * HD + scol + 8);           \
    }                                                                      \
    vr0 = *(const bf16x8*)(Vg + (size_t)srow * S + (KT) * 64 + scol);      \
    vr1 = *(const bf16x8*)(Vg + (size_t)srow * S + (KT) * 64 + scol + 8);  \
  }

  int vw = 0;

  {
    __builtin_amdgcn_s_setprio(1);
    QKBURST(&Ks[0][0], scA0, scA1);
    __builtin_amdgcn_s_setprio(0);
    STAGEWR(0);
    __syncthreads();
    vw = 1;
  }

  {
    LOADS(1);
    __builtin_amdgcn_s_setprio(1);
    QKBURST(&Ks[1][0], scB0, scB1);
    __builtin_amdgcn_s_setprio(0);
    EXPPACK(scA0, scA1, pBA);
    STAGEWR(1);
    __syncthreads();
    vw = 2;
  }

#define STEP(KT, SCN0, SCN1, SCP0, SCP1, PBN, PBO)                    \
  {                                                                   \
    LOADS(KT);                                                        \
    const int vr2 = (vw + 1 == 3) ? 0 : vw + 1; /* (t-2)%3 */         \
    __builtin_amdgcn_s_setprio(1);                                    \
    QKBURST(&Ks[(KT)&1][0], SCN0, SCN1);                              \
    PVBURST(&Vs[vr2][0], PBO);                                        \
    __builtin_amdgcn_s_setprio(0);                                    \
    EXPPACK(SCP0, SCP1, PBN);                                         \
    STAGEWR(KT);                                                      \
    __syncthreads();                                                  \
    vw = (vw == 2) ? 0 : vw + 1;                                      \
  }

  for (int kt = 2; kt < NT; kt += 2) {
    STEP(kt, scA0, scA1, scB0, scB1, pBB, pBA);
    STEP(kt + 1, scB0, scB1, scA0, scA1, pBA, pBB);
  }

  {
    __builtin_amdgcn_s_setprio(1);
    PVBURST(&Vs[0][0], pBA);  // PV(30)
    __builtin_amdgcn_s_setprio(0);
    EXPPACK(scB0, scB1, pBB);
    __builtin_amdgcn_s_setprio(1);
    PVBURST(&Vs[1][0], pBB);  // PV(31)
    __builtin_amdgcn_s_setprio(0);
  }
#undef STEP
#undef LOADS
#undef STAGEWR
#undef PVBURST
#undef QKBURST
#undef EXPPACK

  const float inv = 1.0f / lsum[0];
  const int b = bh >> 2, hh = bh & 3;
  short* ap = Abf + ((size_t)b * S + qrow + q31) * 256 + hh * 64;
#pragma unroll
  for (int dt = 0; dt < 2; ++dt) {
    const f32x16& o = dt ? o1 : o0;
#pragma unroll
    for (int g = 0; g < 4; ++g) {
      const int d0 = dt * 32 + 8 * g + 4 * h;
      bf16x4 r = pk4(o[4 * g + 0] * inv, o[4 * g + 1] * inv,
                     o[4 * g + 2] * inv, o[4 * g + 3] * inv);
      *(bf16x4*)(ap + d0) = r;
    }
  }
}

}  // namespace

extern "C" void kernel_launch(void* const* d_in, const int* in_sizes, int n_in,
                              void* d_out, int out_size, void* d_ws, size_t ws_size,
                              hipStream_t stream) {
  const float* x  = (const float*)d_in[0];
  const float* Wq = (const float*)d_in[1];
  const float* bq = (const float*)d_in[2];
  const float* Wk = (const float*)d_in[3];
  const float* bk = (const float*)d_in[4];
  const float* Wv = (const float*)d_in[5];
  const float* bv = (const float*)d_in[6];
  const float* Wo = (const float*)d_in[7];
  const float* bo = (const float*)d_in[8];
  float* out = (float*)d_out;

  const size_t per = (size_t)M * D;
  short* WqT = (short*)d_ws;
  short* WkT = WqT + 256 * 256;
  short* WvT = WkT + 256 * 256;
  short* WoT = WvT + 256 * 256;
  short* Qbf = WoT + 256 * 256;
  short* Kbf = Qbf + per;
  short* Vt  = Kbf + per;          // [bh][d][s]
  short* Abf = Vt + per;

  prep_w_kernel<<<64, 256, 0, stream>>>(Wq, Wk, Wv, Wo, WqT, WkT, WvT, WoT);
  gemm_qkv_kernel<<<dim3(256, 3), 256, 0, stream>>>(x, WqT, WkT, WvT, bq, bk, bv,
                                                    Qbf, Kbf, Vt);
  attn_kernel15<<<512, 256, 0, stream>>>(Qbf, Kbf, Vt, Abf);
  gemm_out_kernel<<<256, 256, 0, stream>>>(Abf, WoT, bo, out);
}